// Round 1
// baseline (178.539 us; speedup 1.0000x reference)
//
#include <hip/hip_runtime.h>
#include <hip/hip_bf16.h>

#define SVOL 110592   // 48*48*48 voxels
#define HD   2304     // 48*48
#define NDIM 48

typedef __attribute__((ext_vector_type(4))) float f32x4;
typedef __attribute__((ext_vector_type(8))) short bf16x8;
typedef unsigned short ushort_t;
typedef unsigned int uint_t;

// ---------------- Kernel 0: W fp32 -> bf16 ----------------
__global__ __launch_bounds__(256) void wconv_kernel(const float* __restrict__ W,
                                                    ushort_t* __restrict__ Wb) {
    int i = blockIdx.x * 256 + threadIdx.x;   // grid covers 128*256 = 32768 exactly
    float f = W[i];
    __hip_bfloat16 h = __float2bfloat16(f);
    Wb[i] = *(ushort_t*)&h;
}

// ---------------- Kernel 1: per-(b,c) parity-min tables + y staging ----------------
// ybf layout: [B][2C][SVOL] bf16;  c<128 -> bf16(x),  c>=128 -> bf16(xj)
__global__ __launch_bounds__(512) void prep_kernel(const float* __restrict__ x,
                                                   ushort_t* __restrict__ ybf) {
    __shared__ float tabD[HD * 2];   // line (h,w), parity of d
    __shared__ float tabH[HD * 2];   // line (d,w), parity of h
    __shared__ float tabW[HD * 2];   // line (d,h), parity of w
    const int bc = blockIdx.x;                 // b*128 + c
    const float* __restrict__ xp = x + (size_t)bc * SVOL;
    const int t = threadIdx.x;

    // D-axis lines: l = h*48+w ; fully coalesced HBM read
    for (int l = t; l < HD; l += 512) {
        float m0 = 3e38f, m1 = 3e38f;
        #pragma unroll
        for (int d = 0; d < NDIM; d += 2) {
            m0 = fminf(m0, xp[(size_t)d * HD + l]);
            m1 = fminf(m1, xp[(size_t)(d + 1) * HD + l]);
        }
        tabD[l * 2 + 0] = m0; tabD[l * 2 + 1] = m1;
    }
    // H-axis lines: l = d*48+w
    for (int l = t; l < HD; l += 512) {
        int d = l / NDIM, w = l - d * NDIM;
        const float* p = xp + (size_t)d * HD + w;
        float m0 = 3e38f, m1 = 3e38f;
        #pragma unroll
        for (int h = 0; h < NDIM; h += 2) {
            m0 = fminf(m0, p[h * NDIM]);
            m1 = fminf(m1, p[(h + 1) * NDIM]);
        }
        tabH[l * 2 + 0] = m0; tabH[l * 2 + 1] = m1;
    }
    // W-axis lines: l = d*48+h ; per-thread contiguous float4 reads
    for (int l = t; l < HD; l += 512) {
        const float* p = xp + (size_t)l * NDIM;
        float m0 = 3e38f, m1 = 3e38f;
        #pragma unroll
        for (int q = 0; q < NDIM / 4; ++q) {
            f32x4 v = *(const f32x4*)(p + q * 4);
            m0 = fminf(m0, fminf(v[0], v[2]));
            m1 = fminf(m1, fminf(v[1], v[3]));
        }
        tabW[l * 2 + 0] = m0; tabW[l * 2 + 1] = m1;
    }
    __syncthreads();

    const int b = bc >> 7, c = bc & 127;
    ushort_t* yx = ybf + (size_t)(b * 256 + c) * SVOL;
    ushort_t* yj = ybf + (size_t)(b * 256 + 128 + c) * SVOL;
    for (int i4 = t; i4 < SVOL / 4; i4 += 512) {
        const int s = i4 * 4;
        f32x4 v = *(const f32x4*)(xp + s);
        int d = s / HD;
        int r = s - d * HD;          // = h*48 + w0
        int h = r / NDIM;
        int w0 = r - h * NDIM;       // multiple of 4
        const int pd = d & 1, ph = h & 1;
        const float mW0 = tabW[(d * NDIM + h) * 2 + 0];
        const float mW1 = tabW[(d * NDIM + h) * 2 + 1];
        union { __hip_bfloat16 h4[4]; uint2 u; } ox, oj;
        #pragma unroll
        for (int j = 0; j < 4; ++j) {
            float xv = v[j];
            float mD = tabD[(r + j) * 2 + pd];
            float mH = tabH[(d * NDIM + w0 + j) * 2 + ph];
            float mm = fminf(mD, fminf(mH, (j & 1) ? mW1 : mW0));
            float xjv = fmaxf(0.0f, xv - mm);
            ox.h4[j] = __float2bfloat16(xv);
            oj.h4[j] = __float2bfloat16(xjv);
        }
        *(uint2*)(yx + s) = ox.u;
        *(uint2*)(yj + s) = oj.u;
    }
}

// ---------------- Kernel 2: fused transpose-stage + bf16 MFMA GEMM ----------------
// out[b][o][s] = relu( sum_c Wb[o][c] * ybf[b][c][s] + bias[o] )
// Block: 512 threads (8 waves, 2 M x 4 N), tile 128 o x 128 s, K=256 staged once.
__global__ __launch_bounds__(512) void gemm_kernel(const ushort_t* __restrict__ ybf,
                                                   const ushort_t* __restrict__ Wb,
                                                   const float* __restrict__ bias,
                                                   float* __restrict__ out) {
    __shared__ uint4 ytile[128 * 32];   // [s][32 chunks of 16B] = 64 KB, XOR-swizzled
    const int s0 = blockIdx.x * 128;
    const int b  = blockIdx.y;
    const int t  = threadIdx.x;
    const ushort_t* __restrict__ yb = ybf + (size_t)b * 256 * SVOL;

    // Build y tile: gather 8 channels per task (the [c][s] -> [s][c] transpose)
    {
        const int s_in = t & 127;
        const int o0   = t >> 7;          // 0..3
        const int sw   = s_in & 7;
        #pragma unroll
        for (int it = 0; it < 8; ++it) {
            const int oct = it * 4 + o0;  // 0..31  (chunk of 8 channels)
            const ushort_t* src = yb + (size_t)oct * 8 * SVOL + (s0 + s_in);
            ushort_t e[8];
            #pragma unroll
            for (int j = 0; j < 8; ++j) e[j] = src[(size_t)j * SVOL];
            uint4 pk;
            pk.x = (uint_t)e[0] | ((uint_t)e[1] << 16);
            pk.y = (uint_t)e[2] | ((uint_t)e[3] << 16);
            pk.z = (uint_t)e[4] | ((uint_t)e[5] << 16);
            pk.w = (uint_t)e[6] | ((uint_t)e[7] << 16);
            ytile[s_in * 32 + (oct ^ sw)] = pk;
        }
    }
    __syncthreads();

    const int wid = t >> 6, lane = t & 63;
    const int wm = wid >> 2;          // 0..1 : 64-o half
    const int wn = wid & 3;           // 0..3 : 32-s quarter
    const int l15 = lane & 15, l4 = lane >> 4;

    f32x4 acc[4][2] = {};
    const ushort_t* wp = Wb + (size_t)(wm * 64 + l15) * 256 + l4 * 8;
    const char* ylds = (const char*)ytile;

    #pragma unroll
    for (int kk = 0; kk < 8; ++kk) {
        bf16x8 a[4], bb[2];
        #pragma unroll
        for (int m = 0; m < 4; ++m)
            a[m] = *(const bf16x8*)(wp + ((size_t)m * 16 * 256 + kk * 32));
        #pragma unroll
        for (int n = 0; n < 2; ++n) {
            const int s_in = wn * 32 + n * 16 + l15;
            const int chunk = (kk * 4 + l4) ^ (s_in & 7);
            bb[n] = *(const bf16x8*)(ylds + s_in * 512 + chunk * 16);
        }
        #pragma unroll
        for (int m = 0; m < 4; ++m)
            #pragma unroll
            for (int n = 0; n < 2; ++n)
                acc[m][n] = __builtin_amdgcn_mfma_f32_16x16x32_bf16(a[m], bb[n], acc[m][n], 0, 0, 0);
    }

    float* ob = out + (size_t)b * 128 * SVOL;
    #pragma unroll
    for (int m = 0; m < 4; ++m) {
        const int o_base = wm * 64 + m * 16 + l4 * 4;
        #pragma unroll
        for (int j = 0; j < 4; ++j) {
            const int o = o_base + j;
            const float bv = bias[o];
            #pragma unroll
            for (int n = 0; n < 2; ++n) {
                const int s = s0 + wn * 32 + n * 16 + l15;
                ob[(size_t)o * SVOL + s] = fmaxf(acc[m][n][j] + bv, 0.0f);
            }
        }
    }
}

extern "C" void kernel_launch(void* const* d_in, const int* in_sizes, int n_in,
                              void* d_out, int out_size, void* d_ws, size_t ws_size,
                              hipStream_t stream) {
    const float* x    = (const float*)d_in[0];
    const float* W    = (const float*)d_in[1];
    const float* bias = (const float*)d_in[2];
    float* out = (float*)d_out;

    ushort_t* ybf = (ushort_t*)d_ws;                                    // 113.25 MB
    ushort_t* Wb  = (ushort_t*)((char*)d_ws + (size_t)2 * 256 * SVOL * 2);  // 64 KB

    wconv_kernel<<<128, 256, 0, stream>>>(W, Wb);
    prep_kernel<<<256, 512, 0, stream>>>(x, ybf);
    gemm_kernel<<<dim3(SVOL / 128, 2), 512, 0, stream>>>(ybf, Wb, bias, out);
}

// Round 3
// 171.119 us; speedup vs baseline: 1.0434x; 1.0434x over previous
//
#include <hip/hip_runtime.h>
#include <hip/hip_bf16.h>

#define SVOL 110592   // 48*48*48 voxels
#define HD   2304     // 48*48
#define NDIM 48

typedef __attribute__((ext_vector_type(4))) float f32x4;
typedef __attribute__((ext_vector_type(8))) short bf16x8;
typedef __attribute__((ext_vector_type(2))) unsigned int u32x2;
typedef unsigned short ushort_t;
typedef unsigned int uint_t;

// ---------------- Kernel 0: W fp32 -> bf16 ----------------
__global__ __launch_bounds__(256) void wconv_kernel(const float* __restrict__ W,
                                                    ushort_t* __restrict__ Wb) {
    int i = blockIdx.x * 256 + threadIdx.x;   // 128*256 = 32768 exactly
    float f = W[i];
    __hip_bfloat16 h = __float2bfloat16(f);
    Wb[i] = *(ushort_t*)&h;
}

// ---------------- Kernel 1: parity-min tables, slab-local re-reads ----------------
// tabD[bc][p][h*48+w], tabH[bc][p][d*48+w], tabW[bc][p][d*48+h]
__global__ __launch_bounds__(512) void tables_kernel(const float* __restrict__ x,
                                                     float* __restrict__ tabD,
                                                     float* __restrict__ tabH,
                                                     float* __restrict__ tabW) {
    const int bc = blockIdx.x;
    const float* __restrict__ xp = x + (size_t)bc * SVOL;
    const int t = threadIdx.x;

    float accD[5][2];
    #pragma unroll
    for (int k = 0; k < 5; ++k) { accD[k][0] = 3e38f; accD[k][1] = 3e38f; }

    for (int slab = 0; slab < 6; ++slab) {
        const float* __restrict__ sp = xp + (size_t)slab * 8 * HD;
        // D-pass: fetches the whole slab from HBM, coalesced
        #pragma unroll
        for (int k = 0; k < 5; ++k) {
            const int l = t + k * 512;
            if (l < HD) {
                #pragma unroll
                for (int dl = 0; dl < 8; dl += 2) {
                    accD[k][0] = fminf(accD[k][0], sp[(size_t)dl * HD + l]);
                    accD[k][1] = fminf(accD[k][1], sp[(size_t)(dl + 1) * HD + l]);
                }
            }
        }
        // H-pass: slab is L2-hot
        if (t < 384) {
            const int dl = t / NDIM, w = t - dl * NDIM;
            const float* p = sp + (size_t)dl * HD + w;
            float m0 = 3e38f, m1 = 3e38f;
            #pragma unroll
            for (int h = 0; h < NDIM; h += 2) {
                m0 = fminf(m0, p[h * NDIM]);
                m1 = fminf(m1, p[(h + 1) * NDIM]);
            }
            const int d = slab * 8 + dl;
            tabH[(size_t)bc * 2 * HD + d * NDIM + w]      = m0;
            tabH[(size_t)bc * 2 * HD + HD + d * NDIM + w] = m1;
        }
        // W-pass
        if (t < 384) {
            const int dl = t / NDIM, h = t - dl * NDIM;
            const float* p = sp + (size_t)dl * HD + h * NDIM;
            float m0 = 3e38f, m1 = 3e38f;
            #pragma unroll
            for (int q = 0; q < NDIM / 4; ++q) {
                f32x4 v = *(const f32x4*)(p + q * 4);
                m0 = fminf(m0, fminf(v[0], v[2]));
                m1 = fminf(m1, fminf(v[1], v[3]));
            }
            const int d = slab * 8 + dl;
            tabW[(size_t)bc * 2 * HD + d * NDIM + h]      = m0;
            tabW[(size_t)bc * 2 * HD + HD + d * NDIM + h] = m1;
        }
    }
    #pragma unroll
    for (int k = 0; k < 5; ++k) {
        const int l = t + k * 512;
        if (l < HD) {
            tabD[(size_t)bc * 2 * HD + l]      = accD[k][0];
            tabD[(size_t)bc * 2 * HD + HD + l] = accD[k][1];
        }
    }
}

// ---------------- Kernel 2: element pass -> ybf [b][2C][SVOL] bf16 ----------------
__global__ __launch_bounds__(256) void elem_kernel(const float* __restrict__ x,
                                                   const float* __restrict__ tabD,
                                                   const float* __restrict__ tabH,
                                                   const float* __restrict__ tabW,
                                                   ushort_t* __restrict__ ybf) {
    __shared__ __align__(16) float sD[2 * HD];    // [p][h*48+w]
    __shared__ __align__(16) float sH[2 * 384];   // [p][dl*48+w]
    __shared__ __align__(16) float sW[2 * 384];   // [p][dl*48+h]
    const int slab = blockIdx.x;    // 0..5
    const int bc   = blockIdx.y;    // 0..255
    const int t    = threadIdx.x;
    const int b = bc >> 7, c = bc & 127;

    const float* tD = tabD + (size_t)bc * 2 * HD;
    for (int i = t; i < 2 * HD / 4; i += 256)
        ((f32x4*)sD)[i] = ((const f32x4*)tD)[i];
    const float* tH = tabH + (size_t)bc * 2 * HD;
    const float* tW = tabW + (size_t)bc * 2 * HD;
    for (int i = t; i < 96; i += 256) {
        ((f32x4*)sH)[i]      = ((const f32x4*)(tH + slab * 384))[i];
        ((f32x4*)sH)[96 + i] = ((const f32x4*)(tH + HD + slab * 384))[i];
        ((f32x4*)sW)[i]      = ((const f32x4*)(tW + slab * 384))[i];
        ((f32x4*)sW)[96 + i] = ((const f32x4*)(tW + HD + slab * 384))[i];
    }
    __syncthreads();

    const float* __restrict__ xp = x + (size_t)bc * SVOL + (size_t)slab * 8 * HD;
    ushort_t* yx = ybf + (size_t)(b * 256 + c) * SVOL + (size_t)slab * 8 * HD;
    ushort_t* yj = yx + (size_t)128 * SVOL;

    for (int i4 = t; i4 < 8 * HD / 4; i4 += 256) {
        const int s = i4 * 4;
        const int dl = s / HD;
        const int r  = s - dl * HD;        // h*48 + w0, mult of 4
        const int h  = r / NDIM;
        const int w0 = r - h * NDIM;       // mult of 4
        const int pd = dl & 1, ph = h & 1;

        f32x4 v  = *(const f32x4*)(xp + s);
        f32x4 mD = *(const f32x4*)(sD + pd * HD + r);
        f32x4 mH = *(const f32x4*)(sH + ph * 384 + dl * NDIM + w0);
        const float mW0 = sW[dl * NDIM + h];
        const float mW1 = sW[384 + dl * NDIM + h];

        union { __hip_bfloat16 h4[4]; uint2 u; } ox, oj;
        #pragma unroll
        for (int j = 0; j < 4; ++j) {
            const float mm  = fminf(mD[j], fminf(mH[j], (j & 1) ? mW1 : mW0));
            const float xjv = fmaxf(0.0f, v[j] - mm);
            ox.h4[j] = __float2bfloat16(v[j]);
            oj.h4[j] = __float2bfloat16(xjv);
        }
        *(uint2*)(yx + s) = ox.u;
        *(uint2*)(yj + s) = oj.u;
    }
}

// ---------------- Kernel 3: GEMM, global_load_lds staging + tr_b16 B-frags ----------------
// LDS tile: [cq 0..63][sq 0..7][row 0..3][col 0..15] ushort  (subtiled [c][s], 64 KB)
__global__ __launch_bounds__(512) void gemm_kernel(const ushort_t* __restrict__ ybf,
                                                   const ushort_t* __restrict__ Wb,
                                                   const float* __restrict__ bias,
                                                   float* __restrict__ out) {
    __shared__ __align__(1024) ushort_t ytile[32768];   // 64 KB
    const int s0 = blockIdx.x * 128;
    const int b  = blockIdx.y;
    const int t  = threadIdx.x;
    const int wid = t >> 6, lane = t & 63;
    const ushort_t* __restrict__ yb = ybf + (size_t)b * 256 * SVOL;

    // Stage 64 KB: each wave-instr fills one cq block (1 KB); linear LDS dest,
    // per-lane global src: lane covers (row = c&3, 8 consecutive s).
    {
        const int sq   = lane >> 3;
        const int row  = (lane >> 1) & 3;
        const int colh = lane & 1;
        #pragma unroll
        for (int it = 0; it < 8; ++it) {
            const int cq = it * 8 + wid;
            const ushort_t* src = yb + (size_t)(cq * 4 + row) * SVOL + (s0 + sq * 16 + colh * 8);
            __builtin_amdgcn_global_load_lds(
                (const __attribute__((address_space(1))) void*)src,
                (__attribute__((address_space(3))) void*)&ytile[cq * 512],
                16, 0, 0);
        }
    }
    __syncthreads();

    const int wm = wid >> 2;          // 0..1 : 64-o half
    const int wn = wid & 3;           // 0..3 : 32-s quarter
    const int l15 = lane & 15, l4 = lane >> 4;

    f32x4 acc[4][2] = {};
    const ushort_t* wp = Wb + (size_t)(wm * 64 + l15) * 256 + l4 * 8;
    const uint_t lds_base = (uint_t)(uintptr_t)(__attribute__((address_space(3))) ushort_t*)ytile;
    // tr_read: 16-lane group assembles 16 lane-fetches of 8B into a 4x16 bf16
    // matrix; lane receives column l15. So per-lane addr = subtile_base + l15*8.
    // subtile for (kk,n): cq0 = kk*8 + l4*2 (+1 via offset:1024), sq = wn*2+n.
    const uint_t addr0 = lds_base + (uint_t)(l4 * 2048 + wn * 256 + l15 * 8);

    #pragma unroll
    for (int kk = 0; kk < 8; ++kk) {
        bf16x8 a[4], bb[2];
        #pragma unroll
        for (int m = 0; m < 4; ++m)
            a[m] = *(const bf16x8*)(wp + ((size_t)m * 16 * 256 + kk * 32));
        u32x2 lo[2], hi[2];
        #pragma unroll
        for (int n = 0; n < 2; ++n) {
            const uint_t ad = addr0 + (uint_t)(kk * 8192 + n * 128);
            asm volatile("ds_read_b64_tr_b16 %0, %2 offset:0\n\t"
                         "ds_read_b64_tr_b16 %1, %2 offset:1024"
                         : "=&v"(lo[n]), "=&v"(hi[n]) : "v"(ad) : "memory");
        }
        asm volatile("s_waitcnt lgkmcnt(0)" ::: "memory");
        __builtin_amdgcn_sched_barrier(0);
        #pragma unroll
        for (int n = 0; n < 2; ++n) {
            union { u32x2 u2[2]; bf16x8 v; } cvt;
            cvt.u2[0] = lo[n]; cvt.u2[1] = hi[n];
            bb[n] = cvt.v;
        }
        #pragma unroll
        for (int m = 0; m < 4; ++m)
            #pragma unroll
            for (int n = 0; n < 2; ++n)
                acc[m][n] = __builtin_amdgcn_mfma_f32_16x16x32_bf16(a[m], bb[n], acc[m][n], 0, 0, 0);
    }

    float* ob = out + (size_t)b * 128 * SVOL;
    #pragma unroll
    for (int m = 0; m < 4; ++m) {
        const int o_base = wm * 64 + m * 16 + l4 * 4;
        #pragma unroll
        for (int j = 0; j < 4; ++j) {
            const int o = o_base + j;
            const float bv = bias[o];
            #pragma unroll
            for (int n = 0; n < 2; ++n) {
                const int s = s0 + wn * 32 + n * 16 + l15;
                ob[(size_t)o * SVOL + s] = fmaxf(acc[m][n][j] + bv, 0.0f);
            }
        }
    }
}

extern "C" void kernel_launch(void* const* d_in, const int* in_sizes, int n_in,
                              void* d_out, int out_size, void* d_ws, size_t ws_size,
                              hipStream_t stream) {
    const float* x    = (const float*)d_in[0];
    const float* W    = (const float*)d_in[1];
    const float* bias = (const float*)d_in[2];
    float* out = (float*)d_out;

    ushort_t* ybf = (ushort_t*)d_ws;                                       // 113.25 MB
    ushort_t* Wb  = (ushort_t*)((char*)d_ws + (size_t)2 * 256 * SVOL * 2); // 64 KB

    // Tables live in d_out scratch space (gemm fully overwrites out afterwards).
    float* tabD = (float*)d_out;                 // 256*2*2304 floats = 4.5 MB
    float* tabH = tabD + (size_t)256 * 2 * HD;
    float* tabW = tabH + (size_t)256 * 2 * HD;   // total 13.5 MB < 113 MB out

    wconv_kernel<<<128, 256, 0, stream>>>(W, Wb);
    tables_kernel<<<256, 512, 0, stream>>>(x, tabD, tabH, tabW);
    elem_kernel<<<dim3(6, 256), 256, 0, stream>>>(x, tabD, tabH, tabW, ybf);
    gemm_kernel<<<dim3(SVOL / 128, 2), 512, 0, stream>>>(ybf, Wb, bias, out);
}

// Round 4
// 163.289 us; speedup vs baseline: 1.0934x; 1.0480x over previous
//
#include <hip/hip_runtime.h>
#include <hip/hip_bf16.h>

#define SVOL 110592   // 48*48*48 voxels
#define HD   2304     // 48*48
#define NDIM 48

typedef __attribute__((ext_vector_type(4))) float f32x4;
typedef __attribute__((ext_vector_type(8))) short bf16x8;
typedef __attribute__((ext_vector_type(2))) unsigned int u32x2;
typedef unsigned short ushort_t;
typedef unsigned int uint_t;

// ---------------- Kernel 0: W fp32 -> bf16 ----------------
__global__ __launch_bounds__(256) void wconv_kernel(const float* __restrict__ W,
                                                    ushort_t* __restrict__ Wb) {
    int i = blockIdx.x * 256 + threadIdx.x;   // 128*256 = 32768 exactly
    float f = W[i];
    __hip_bfloat16 h = __float2bfloat16(f);
    Wb[i] = *(ushort_t*)&h;
}

// ---------------- Kernel 1: parity-min tables, 3 partial blocks per bc ----------------
// tabDp[part][bc][p][h*48+w] (partial min over part's 16 d-planes)
// tabH[bc][p][d*48+w], tabW[bc][p][d*48+h]  (d-rows partitioned across parts)
__global__ __launch_bounds__(512) void tables_kernel(const float* __restrict__ x,
                                                     float* __restrict__ tabDp,
                                                     float* __restrict__ tabH,
                                                     float* __restrict__ tabW) {
    const int bc   = blockIdx.x;
    const int part = blockIdx.y;           // 0..2, two 8-plane slabs each
    const float* __restrict__ xp = x + (size_t)bc * SVOL;
    const int t = threadIdx.x;

    float accD[5][2];
    #pragma unroll
    for (int k = 0; k < 5; ++k) { accD[k][0] = 3e38f; accD[k][1] = 3e38f; }

    for (int sl = 0; sl < 2; ++sl) {
        const int slab = part * 2 + sl;
        const float* __restrict__ sp = xp + (size_t)slab * 8 * HD;
        // D-pass: coalesced read of the slab
        #pragma unroll
        for (int k = 0; k < 5; ++k) {
            const int l = t + k * 512;
            if (l < HD) {
                #pragma unroll
                for (int dl = 0; dl < 8; dl += 2) {
                    accD[k][0] = fminf(accD[k][0], sp[(size_t)dl * HD + l]);
                    accD[k][1] = fminf(accD[k][1], sp[(size_t)(dl + 1) * HD + l]);
                }
            }
        }
        // H-pass (slab hot in L2/L3)
        if (t < 384) {
            const int dl = t / NDIM, w = t - dl * NDIM;
            const float* p = sp + (size_t)dl * HD + w;
            float m0 = 3e38f, m1 = 3e38f;
            #pragma unroll
            for (int h = 0; h < NDIM; h += 2) {
                m0 = fminf(m0, p[h * NDIM]);
                m1 = fminf(m1, p[(h + 1) * NDIM]);
            }
            const int d = slab * 8 + dl;
            tabH[(size_t)bc * 2 * HD + d * NDIM + w]      = m0;
            tabH[(size_t)bc * 2 * HD + HD + d * NDIM + w] = m1;
        }
        // W-pass
        if (t < 384) {
            const int dl = t / NDIM, h = t - dl * NDIM;
            const float* p = sp + (size_t)dl * HD + h * NDIM;
            float m0 = 3e38f, m1 = 3e38f;
            #pragma unroll
            for (int q = 0; q < NDIM / 4; ++q) {
                f32x4 v = *(const f32x4*)(p + q * 4);
                m0 = fminf(m0, fminf(v[0], v[2]));
                m1 = fminf(m1, fminf(v[1], v[3]));
            }
            const int d = slab * 8 + dl;
            tabW[(size_t)bc * 2 * HD + d * NDIM + h]      = m0;
            tabW[(size_t)bc * 2 * HD + HD + d * NDIM + h] = m1;
        }
    }
    float* tDo = tabDp + ((size_t)part * 256 + bc) * 2 * HD;
    #pragma unroll
    for (int k = 0; k < 5; ++k) {
        const int l = t + k * 512;
        if (l < HD) { tDo[l] = accD[k][0]; tDo[HD + l] = accD[k][1]; }
    }
}

// ---------------- Kernel 2: element pass -> ybf [b][2C][SVOL] bf16 ----------------
__global__ __launch_bounds__(256) void elem_kernel(const float* __restrict__ x,
                                                   const float* __restrict__ tabDp,
                                                   const float* __restrict__ tabH,
                                                   const float* __restrict__ tabW,
                                                   ushort_t* __restrict__ ybf) {
    __shared__ __align__(16) float sD[2 * HD];    // [p][h*48+w]  (min of 3 partials)
    __shared__ __align__(16) float sH[2 * 384];   // [p][dl*48+w]
    __shared__ __align__(16) float sW[2 * 384];   // [p][dl*48+h]
    const int slab = blockIdx.x;    // 0..5
    const int bc   = blockIdx.y;    // 0..255
    const int t    = threadIdx.x;
    const int b = bc >> 7, c = bc & 127;

    const float* tD0 = tabDp + ((size_t)0 * 256 + bc) * 2 * HD;
    const float* tD1 = tabDp + ((size_t)1 * 256 + bc) * 2 * HD;
    const float* tD2 = tabDp + ((size_t)2 * 256 + bc) * 2 * HD;
    for (int i = t; i < 2 * HD / 4; i += 256) {
        f32x4 a = ((const f32x4*)tD0)[i];
        f32x4 d1 = ((const f32x4*)tD1)[i];
        f32x4 d2 = ((const f32x4*)tD2)[i];
        f32x4 m;
        #pragma unroll
        for (int j = 0; j < 4; ++j) m[j] = fminf(a[j], fminf(d1[j], d2[j]));
        ((f32x4*)sD)[i] = m;
    }
    const float* tH = tabH + (size_t)bc * 2 * HD;
    const float* tW = tabW + (size_t)bc * 2 * HD;
    for (int i = t; i < 96; i += 256) {
        ((f32x4*)sH)[i]      = ((const f32x4*)(tH + slab * 384))[i];
        ((f32x4*)sH)[96 + i] = ((const f32x4*)(tH + HD + slab * 384))[i];
        ((f32x4*)sW)[i]      = ((const f32x4*)(tW + slab * 384))[i];
        ((f32x4*)sW)[96 + i] = ((const f32x4*)(tW + HD + slab * 384))[i];
    }
    __syncthreads();

    const float* __restrict__ xp = x + (size_t)bc * SVOL + (size_t)slab * 8 * HD;
    ushort_t* yx = ybf + (size_t)(b * 256 + c) * SVOL + (size_t)slab * 8 * HD;
    ushort_t* yj = yx + (size_t)128 * SVOL;

    for (int i4 = t; i4 < 8 * HD / 4; i4 += 256) {
        const int s = i4 * 4;
        const int dl = s / HD;
        const int r  = s - dl * HD;        // h*48 + w0, mult of 4
        const int h  = r / NDIM;
        const int w0 = r - h * NDIM;       // mult of 4
        const int pd = dl & 1, ph = h & 1;

        f32x4 v  = *(const f32x4*)(xp + s);
        f32x4 mD = *(const f32x4*)(sD + pd * HD + r);
        f32x4 mH = *(const f32x4*)(sH + ph * 384 + dl * NDIM + w0);
        const float mW0 = sW[dl * NDIM + h];
        const float mW1 = sW[384 + dl * NDIM + h];

        union { __hip_bfloat16 h4[4]; uint2 u; } ox, oj;
        #pragma unroll
        for (int j = 0; j < 4; ++j) {
            const float mm  = fminf(mD[j], fminf(mH[j], (j & 1) ? mW1 : mW0));
            const float xjv = fmaxf(0.0f, v[j] - mm);
            ox.h4[j] = __float2bfloat16(v[j]);
            oj.h4[j] = __float2bfloat16(xjv);
        }
        *(uint2*)(yx + s) = ox.u;
        *(uint2*)(yj + s) = oj.u;
    }
}

// ---------------- Kernel 3: GEMM 128o x 64s, 4 waves, 2-phase batched tr_reads ----------------
// LDS tile: [cq 0..63][sq 0..3][row 0..3][col 0..15] ushort = 32 KB
__global__ __launch_bounds__(256, 3) void gemm_kernel(const ushort_t* __restrict__ ybf,
                                                      const ushort_t* __restrict__ Wb,
                                                      const float* __restrict__ bias,
                                                      float* __restrict__ out) {
    __shared__ __align__(1024) ushort_t ytile[16384];   // 32 KB
    const int s0 = blockIdx.x * 64;
    const int b  = blockIdx.y;
    const int t  = threadIdx.x;
    const int wid = t >> 6, lane = t & 63;   // 4 waves
    const ushort_t* __restrict__ yb = ybf + (size_t)b * 256 * SVOL;

    // Stage 32 KB: 8 instrs/wave, each 1 KB = 2 cq subtiles (512 B each).
    {
        const int g    = lane >> 5;          // which cq of the pair
        const int l5   = lane & 31;
        const int sq   = l5 >> 3;            // 0..3
        const int row  = (l5 >> 1) & 3;      // 0..3
        const int colh = l5 & 1;             // 0/1
        #pragma unroll
        for (int it = 0; it < 8; ++it) {
            const int cq0 = (it * 4 + wid) * 2;
            const int c   = (cq0 + g) * 4 + row;
            const ushort_t* src = yb + (size_t)c * SVOL + (s0 + sq * 16 + colh * 8);
            __builtin_amdgcn_global_load_lds(
                (const __attribute__((address_space(1))) void*)src,
                (__attribute__((address_space(3))) void*)&ytile[cq0 * 256],
                16, 0, 0);
        }
    }
    __syncthreads();

    const int wm = wid;                      // 32-o strip per wave
    const int l15 = lane & 15, l4 = lane >> 4;

    f32x4 acc[2][4] = {};
    const ushort_t* wp = Wb + (size_t)(wm * 32 + l15) * 256 + l4 * 8;
    const uint_t lds_base = (uint_t)(uintptr_t)(__attribute__((address_space(3))) ushort_t*)ytile;
    // subtile (kk, l4-pair, n): byte = (kk*8 + l4*2)*512 + n*128 + l15*8 ; pair via offset 0/512
    const uint_t addr0 = lds_base + (uint_t)(l4 * 1024 + l15 * 8);

    u32x2 lo[4][4], hi[4][4];
    #pragma unroll
    for (int ph = 0; ph < 2; ++ph) {
        #pragma unroll
        for (int kk = 0; kk < 4; ++kk)
            #pragma unroll
            for (int n = 0; n < 4; ++n) {
                const uint_t ad = addr0 + (uint_t)((ph * 4 + kk) * 4096 + n * 128);
                asm volatile("ds_read_b64_tr_b16 %0, %2 offset:0\n\t"
                             "ds_read_b64_tr_b16 %1, %2 offset:512"
                             : "=&v"(lo[kk][n]), "=&v"(hi[kk][n]) : "v"(ad) : "memory");
            }
        asm volatile("s_waitcnt lgkmcnt(0)" ::: "memory");
        __builtin_amdgcn_sched_barrier(0);
        #pragma unroll
        for (int kk = 0; kk < 4; ++kk) {
            bf16x8 a[2];
            #pragma unroll
            for (int m = 0; m < 2; ++m)
                a[m] = *(const bf16x8*)(wp + ((size_t)m * 16 * 256 + (ph * 4 + kk) * 32));
            #pragma unroll
            for (int n = 0; n < 4; ++n) {
                union { u32x2 u2[2]; bf16x8 v; } cvt;
                cvt.u2[0] = lo[kk][n]; cvt.u2[1] = hi[kk][n];
                #pragma unroll
                for (int m = 0; m < 2; ++m)
                    acc[m][n] = __builtin_amdgcn_mfma_f32_16x16x32_bf16(a[m], cvt.v, acc[m][n], 0, 0, 0);
            }
        }
    }

    float* ob = out + (size_t)b * 128 * SVOL;
    #pragma unroll
    for (int m = 0; m < 2; ++m) {
        const int o_base = wm * 32 + m * 16 + l4 * 4;
        #pragma unroll
        for (int j = 0; j < 4; ++j) {
            const int o = o_base + j;
            const float bv = bias[o];
            #pragma unroll
            for (int n = 0; n < 4; ++n) {
                const int s = s0 + n * 16 + l15;
                ob[(size_t)o * SVOL + s] = fmaxf(acc[m][n][j] + bv, 0.0f);
            }
        }
    }
}

extern "C" void kernel_launch(void* const* d_in, const int* in_sizes, int n_in,
                              void* d_out, int out_size, void* d_ws, size_t ws_size,
                              hipStream_t stream) {
    const float* x    = (const float*)d_in[0];
    const float* W    = (const float*)d_in[1];
    const float* bias = (const float*)d_in[2];
    float* out = (float*)d_out;

    ushort_t* ybf = (ushort_t*)d_ws;                                       // 113.25 MB
    ushort_t* Wb  = (ushort_t*)((char*)d_ws + (size_t)2 * 256 * SVOL * 2); // 64 KB

    // Tables live in d_out scratch (gemm fully overwrites out afterwards).
    float* tabDp = (float*)d_out;                       // 3*256*2*2304*4 = 13.5 MB
    float* tabH  = tabDp + (size_t)3 * 256 * 2 * HD;    // 4.5 MB
    float* tabW  = tabH  + (size_t)256 * 2 * HD;        // 4.5 MB  (total 22.5 < 113)

    wconv_kernel<<<128, 256, 0, stream>>>(W, Wb);
    tables_kernel<<<dim3(256, 3), 512, 0, stream>>>(x, tabDp, tabH, tabW);
    elem_kernel<<<dim3(6, 256), 256, 0, stream>>>(x, tabDp, tabH, tabW, ybf);
    gemm_kernel<<<dim3(SVOL / 64, 2), 256, 0, stream>>>(ybf, Wb, bias, out);
}

// Round 5
// 140.955 us; speedup vs baseline: 1.2666x; 1.1584x over previous
//
#include <hip/hip_runtime.h>
#include <hip/hip_bf16.h>

#define SVOL 110592   // 48*48*48 voxels
#define HD   2304     // 48*48
#define NDIM 48

typedef __attribute__((ext_vector_type(4))) float f32x4;
typedef __attribute__((ext_vector_type(8))) short bf16x8;
typedef __attribute__((ext_vector_type(2))) unsigned int u32x2;
typedef unsigned short ushort_t;
typedef unsigned int uint_t;

// ---------------- Kernel 0: W fp32 -> bf16 ----------------
__global__ __launch_bounds__(256) void wconv_kernel(const float* __restrict__ W,
                                                    ushort_t* __restrict__ Wb) {
    int i = blockIdx.x * 256 + threadIdx.x;   // 128*256 = 32768 exactly
    float f = W[i];
    __hip_bfloat16 h = __float2bfloat16(f);
    Wb[i] = *(ushort_t*)&h;
}

// ---------------- Kernel 1: parity-min tables via LDS-staged plane quads ----------------
// Grid (256 bc, 3 part); part = 16 d-planes = 4 quads of 4 planes.
// tabDp[part][bc][p][h*48+w] (partial min over part's 16 d-planes)
// tabH[bc][p][d*48+w], tabW[bc][p][d*48+h]  (d-rows complete per quad)
__global__ __launch_bounds__(256) void tables_kernel(const float* __restrict__ x,
                                                     float* __restrict__ tabDp,
                                                     float* __restrict__ tabH,
                                                     float* __restrict__ tabW) {
    __shared__ __align__(16) float sl[4 * HD];   // 36 KB: 4 planes, linear
    const int bc   = blockIdx.x;
    const int part = blockIdx.y;     // 0..2
    const float* __restrict__ xp = x + (size_t)bc * SVOL + (size_t)part * 16 * HD;
    const int t    = threadIdx.x;
    const int w4   = t >> 6;         // wave 0..3
    const int lane = t & 63;
    const int dlh  = t / NDIM;       // H/W task split (t < 192): plane-local d
    const int wh   = t - dlh * NDIM; // 0..47: w for H-task, h for W-task

    f32x4 accD[3][2];
    #pragma unroll
    for (int s = 0; s < 3; ++s)
        #pragma unroll
        for (int p = 0; p < 2; ++p)
            #pragma unroll
            for (int e = 0; e < 4; ++e) accD[s][p][e] = 3e38f;

    for (int q = 0; q < 4; ++q) {
        const float* __restrict__ qp = xp + (size_t)q * 4 * HD;
        // Stage 4 planes (9216 floats): 9 x 1KB wave-instrs per wave, linear LDS
        #pragma unroll
        for (int k = 0; k < 9; ++k) {
            const int i16 = (k * 4 + w4) * 64 + lane;     // 16B-chunk id 0..2303
            __builtin_amdgcn_global_load_lds(
                (const __attribute__((address_space(1))) void*)(qp + (size_t)i16 * 4),
                (__attribute__((address_space(3))) void*)&sl[(k * 4 + w4) * 256],
                16, 0, 0);
        }
        __syncthreads();   // drains vmcnt: staged data visible

        // D-fold: col-quads j, lanes consecutive -> conflict-free b128
        #pragma unroll
        for (int s = 0; s < 3; ++s) {
            const int j = t + s * 256;
            if (j < 576) {
                #pragma unroll
                for (int dl = 0; dl < 4; ++dl) {
                    f32x4 v = ((const f32x4*)sl)[dl * 576 + j];
                    #pragma unroll
                    for (int e = 0; e < 4; ++e)
                        accD[s][dl & 1][e] = fminf(accD[s][dl & 1][e], v[e]);
                }
            }
        }
        // H/W folds: 192 tasks (dlh 0..3, wh 0..47), complete per quad
        if (t < 192) {
            const int d = part * 16 + q * 4 + dlh;
            {   // H: min over h at fixed (dlh, w=wh)
                const float* pb = sl + dlh * HD + wh;
                float m0 = 3e38f, m1 = 3e38f;
                #pragma unroll
                for (int h = 0; h < NDIM; h += 2) {
                    m0 = fminf(m0, pb[h * NDIM]);
                    m1 = fminf(m1, pb[(h + 1) * NDIM]);
                }
                tabH[(size_t)bc * 2 * HD + d * NDIM + wh]      = m0;
                tabH[(size_t)bc * 2 * HD + HD + d * NDIM + wh] = m1;
            }
            {   // W: min over w at fixed (dlh, h=wh); rotated j spreads bank-groups
                const f32x4* pr = (const f32x4*)(sl + dlh * HD + wh * NDIM);
                const int rot = wh % 12;
                float m0 = 3e38f, m1 = 3e38f;
                #pragma unroll
                for (int j = 0; j < 12; ++j) {
                    int jj = j + rot; if (jj >= 12) jj -= 12;
                    f32x4 v = pr[jj];
                    m0 = fminf(m0, fminf(v[0], v[2]));
                    m1 = fminf(m1, fminf(v[1], v[3]));
                }
                tabW[(size_t)bc * 2 * HD + d * NDIM + wh]      = m0;
                tabW[(size_t)bc * 2 * HD + HD + d * NDIM + wh] = m1;
            }
        }
        __syncthreads();   // protect sl before next quad's staging
    }

    float* tDo = tabDp + ((size_t)part * 256 + bc) * 2 * HD;
    #pragma unroll
    for (int s = 0; s < 3; ++s) {
        const int j = t + s * 256;
        if (j < 576) {
            *((f32x4*)(tDo + j * 4))      = accD[s][0];
            *((f32x4*)(tDo + HD + j * 4)) = accD[s][1];
        }
    }
}

// ---------------- Kernel 2: element pass -> ybf [b][2C][SVOL] bf16 ----------------
__global__ __launch_bounds__(256) void elem_kernel(const float* __restrict__ x,
                                                   const float* __restrict__ tabDp,
                                                   const float* __restrict__ tabH,
                                                   const float* __restrict__ tabW,
                                                   ushort_t* __restrict__ ybf) {
    __shared__ __align__(16) float sD[2 * HD];    // [p][h*48+w]  (min of 3 partials)
    __shared__ __align__(16) float sH[2 * 384];   // [p][dl*48+w]
    __shared__ __align__(16) float sW[2 * 384];   // [p][dl*48+h]
    const int slab = blockIdx.x;    // 0..5
    const int bc   = blockIdx.y;    // 0..255
    const int t    = threadIdx.x;
    const int b = bc >> 7, c = bc & 127;

    const float* tD0 = tabDp + ((size_t)0 * 256 + bc) * 2 * HD;
    const float* tD1 = tabDp + ((size_t)1 * 256 + bc) * 2 * HD;
    const float* tD2 = tabDp + ((size_t)2 * 256 + bc) * 2 * HD;
    for (int i = t; i < 2 * HD / 4; i += 256) {
        f32x4 a = ((const f32x4*)tD0)[i];
        f32x4 d1 = ((const f32x4*)tD1)[i];
        f32x4 d2 = ((const f32x4*)tD2)[i];
        f32x4 m;
        #pragma unroll
        for (int j = 0; j < 4; ++j) m[j] = fminf(a[j], fminf(d1[j], d2[j]));
        ((f32x4*)sD)[i] = m;
    }
    const float* tH = tabH + (size_t)bc * 2 * HD;
    const float* tW = tabW + (size_t)bc * 2 * HD;
    for (int i = t; i < 96; i += 256) {
        ((f32x4*)sH)[i]      = ((const f32x4*)(tH + slab * 384))[i];
        ((f32x4*)sH)[96 + i] = ((const f32x4*)(tH + HD + slab * 384))[i];
        ((f32x4*)sW)[i]      = ((const f32x4*)(tW + slab * 384))[i];
        ((f32x4*)sW)[96 + i] = ((const f32x4*)(tW + HD + slab * 384))[i];
    }
    __syncthreads();

    const float* __restrict__ xp = x + (size_t)bc * SVOL + (size_t)slab * 8 * HD;
    ushort_t* yx = ybf + (size_t)(b * 256 + c) * SVOL + (size_t)slab * 8 * HD;
    ushort_t* yj = yx + (size_t)128 * SVOL;

    for (int i4 = t; i4 < 8 * HD / 4; i4 += 256) {
        const int s = i4 * 4;
        const int dl = s / HD;
        const int r  = s - dl * HD;        // h*48 + w0, mult of 4
        const int h  = r / NDIM;
        const int w0 = r - h * NDIM;       // mult of 4
        const int pd = dl & 1, ph = h & 1;

        f32x4 v  = *(const f32x4*)(xp + s);
        f32x4 mD = *(const f32x4*)(sD + pd * HD + r);
        f32x4 mH = *(const f32x4*)(sH + ph * 384 + dl * NDIM + w0);
        const float mW0 = sW[dl * NDIM + h];
        const float mW1 = sW[384 + dl * NDIM + h];

        union { __hip_bfloat16 h4[4]; uint2 u; } ox, oj;
        #pragma unroll
        for (int j = 0; j < 4; ++j) {
            const float mm  = fminf(mD[j], fminf(mH[j], (j & 1) ? mW1 : mW0));
            const float xjv = fmaxf(0.0f, v[j] - mm);
            ox.h4[j] = __float2bfloat16(v[j]);
            oj.h4[j] = __float2bfloat16(xjv);
        }
        *(uint2*)(yx + s) = ox.u;
        *(uint2*)(yj + s) = oj.u;
    }
}

// ---------------- Kernel 3: GEMM 128o x 64s, 4 waves, 2-phase batched tr_reads ----------------
// LDS tile: [cq 0..63][sq 0..3][row 0..3][col 0..15] ushort = 32 KB
__global__ __launch_bounds__(256, 3) void gemm_kernel(const ushort_t* __restrict__ ybf,
                                                      const ushort_t* __restrict__ Wb,
                                                      const float* __restrict__ bias,
                                                      float* __restrict__ out) {
    __shared__ __align__(1024) ushort_t ytile[16384];   // 32 KB
    const int s0 = blockIdx.x * 64;
    const int b  = blockIdx.y;
    const int t  = threadIdx.x;
    const int wid = t >> 6, lane = t & 63;   // 4 waves
    const ushort_t* __restrict__ yb = ybf + (size_t)b * 256 * SVOL;

    // Stage 32 KB: 8 instrs/wave, each 1 KB = 2 cq subtiles (512 B each).
    {
        const int g    = lane >> 5;          // which cq of the pair
        const int l5   = lane & 31;
        const int sq   = l5 >> 3;            // 0..3
        const int row  = (l5 >> 1) & 3;      // 0..3
        const int colh = l5 & 1;             // 0/1
        #pragma unroll
        for (int it = 0; it < 8; ++it) {
            const int cq0 = (it * 4 + wid) * 2;
            const int c   = (cq0 + g) * 4 + row;
            const ushort_t* src = yb + (size_t)c * SVOL + (s0 + sq * 16 + colh * 8);
            __builtin_amdgcn_global_load_lds(
                (const __attribute__((address_space(1))) void*)src,
                (__attribute__((address_space(3))) void*)&ytile[cq0 * 256],
                16, 0, 0);
        }
    }
    __syncthreads();

    const int wm = wid;                      // 32-o strip per wave
    const int l15 = lane & 15, l4 = lane >> 4;

    f32x4 acc[2][4] = {};
    const ushort_t* wp = Wb + (size_t)(wm * 32 + l15) * 256 + l4 * 8;
    const uint_t lds_base = (uint_t)(uintptr_t)(__attribute__((address_space(3))) ushort_t*)ytile;
    // subtile (kk, l4-pair, n): byte = (kk*8 + l4*2)*512 + n*128 + l15*8 ; pair via offset 0/512
    const uint_t addr0 = lds_base + (uint_t)(l4 * 1024 + l15 * 8);

    u32x2 lo[4][4], hi[4][4];
    #pragma unroll
    for (int ph = 0; ph < 2; ++ph) {
        #pragma unroll
        for (int kk = 0; kk < 4; ++kk)
            #pragma unroll
            for (int n = 0; n < 4; ++n) {
                const uint_t ad = addr0 + (uint_t)((ph * 4 + kk) * 4096 + n * 128);
                asm volatile("ds_read_b64_tr_b16 %0, %2 offset:0\n\t"
                             "ds_read_b64_tr_b16 %1, %2 offset:512"
                             : "=&v"(lo[kk][n]), "=&v"(hi[kk][n]) : "v"(ad) : "memory");
            }
        asm volatile("s_waitcnt lgkmcnt(0)" ::: "memory");
        __builtin_amdgcn_sched_barrier(0);
        #pragma unroll
        for (int kk = 0; kk < 4; ++kk) {
            bf16x8 a[2];
            #pragma unroll
            for (int m = 0; m < 2; ++m)
                a[m] = *(const bf16x8*)(wp + ((size_t)m * 16 * 256 + (ph * 4 + kk) * 32));
            #pragma unroll
            for (int n = 0; n < 4; ++n) {
                union { u32x2 u2[2]; bf16x8 v; } cvt;
                cvt.u2[0] = lo[kk][n]; cvt.u2[1] = hi[kk][n];
                #pragma unroll
                for (int m = 0; m < 2; ++m)
                    acc[m][n] = __builtin_amdgcn_mfma_f32_16x16x32_bf16(a[m], cvt.v, acc[m][n], 0, 0, 0);
            }
        }
    }

    float* ob = out + (size_t)b * 128 * SVOL;
    #pragma unroll
    for (int m = 0; m < 2; ++m) {
        const int o_base = wm * 32 + m * 16 + l4 * 4;
        #pragma unroll
        for (int j = 0; j < 4; ++j) {
            const int o = o_base + j;
            const float bv = bias[o];
            #pragma unroll
            for (int n = 0; n < 4; ++n) {
                const int s = s0 + n * 16 + l15;
                ob[(size_t)o * SVOL + s] = fmaxf(acc[m][n][j] + bv, 0.0f);
            }
        }
    }
}

extern "C" void kernel_launch(void* const* d_in, const int* in_sizes, int n_in,
                              void* d_out, int out_size, void* d_ws, size_t ws_size,
                              hipStream_t stream) {
    const float* x    = (const float*)d_in[0];
    const float* W    = (const float*)d_in[1];
    const float* bias = (const float*)d_in[2];
    float* out = (float*)d_out;

    ushort_t* ybf = (ushort_t*)d_ws;                                       // 113.25 MB
    ushort_t* Wb  = (ushort_t*)((char*)d_ws + (size_t)2 * 256 * SVOL * 2); // 64 KB

    // Tables live in d_out scratch (gemm fully overwrites out afterwards).
    float* tabDp = (float*)d_out;                       // 3*256*2*2304*4 = 13.5 MB
    float* tabH  = tabDp + (size_t)3 * 256 * 2 * HD;    // 4.5 MB
    float* tabW  = tabH  + (size_t)256 * 2 * HD;        // 4.5 MB  (total 22.5 < 113)

    wconv_kernel<<<128, 256, 0, stream>>>(W, Wb);
    tables_kernel<<<dim3(256, 3), 256, 0, stream>>>(x, tabDp, tabH, tabW);
    elem_kernel<<<dim3(6, 256), 256, 0, stream>>>(x, tabDp, tabH, tabW, ybf);
    gemm_kernel<<<dim3(SVOL / 64, 2), 256, 0, stream>>>(ybf, Wb, bias, out);
}

// Round 6
// 137.365 us; speedup vs baseline: 1.2997x; 1.0261x over previous
//
#include <hip/hip_runtime.h>
#include <hip/hip_bf16.h>

#define SVOL 110592   // 48*48*48 voxels
#define HD   2304     // 48*48
#define NDIM 48

typedef __attribute__((ext_vector_type(4))) float f32x4;
typedef __attribute__((ext_vector_type(8))) short bf16x8;
typedef __attribute__((ext_vector_type(2))) unsigned int u32x2;
typedef unsigned short ushort_t;
typedef unsigned int uint_t;

// ---------------- Kernel 0: W fp32 -> bf16 ----------------
__global__ __launch_bounds__(256) void wconv_kernel(const float* __restrict__ W,
                                                    ushort_t* __restrict__ Wb) {
    int i = blockIdx.x * 256 + threadIdx.x;   // 128*256 = 32768 exactly
    float f = W[i];
    __hip_bfloat16 h = __float2bfloat16(f);
    Wb[i] = *(ushort_t*)&h;
}

// ---------------- Kernel 1: parity-min tables via LDS-staged plane quads ----------------
__global__ __launch_bounds__(256) void tables_kernel(const float* __restrict__ x,
                                                     float* __restrict__ tabDp,
                                                     float* __restrict__ tabH,
                                                     float* __restrict__ tabW) {
    __shared__ __align__(16) float sl[4 * HD];   // 36 KB: 4 planes, linear
    const int bc   = blockIdx.x;
    const int part = blockIdx.y;     // 0..2
    const float* __restrict__ xp = x + (size_t)bc * SVOL + (size_t)part * 16 * HD;
    const int t    = threadIdx.x;
    const int w4   = t >> 6;         // wave 0..3
    const int lane = t & 63;
    const int dlh  = t / NDIM;       // H/W task split (t < 192): plane-local d
    const int wh   = t - dlh * NDIM; // 0..47

    f32x4 accD[3][2];
    #pragma unroll
    for (int s = 0; s < 3; ++s)
        #pragma unroll
        for (int p = 0; p < 2; ++p)
            #pragma unroll
            for (int e = 0; e < 4; ++e) accD[s][p][e] = 3e38f;

    for (int q = 0; q < 4; ++q) {
        const float* __restrict__ qp = xp + (size_t)q * 4 * HD;
        #pragma unroll
        for (int k = 0; k < 9; ++k) {
            const int i16 = (k * 4 + w4) * 64 + lane;
            __builtin_amdgcn_global_load_lds(
                (const __attribute__((address_space(1))) void*)(qp + (size_t)i16 * 4),
                (__attribute__((address_space(3))) void*)&sl[(k * 4 + w4) * 256],
                16, 0, 0);
        }
        __syncthreads();

        #pragma unroll
        for (int s = 0; s < 3; ++s) {
            const int j = t + s * 256;
            if (j < 576) {
                #pragma unroll
                for (int dl = 0; dl < 4; ++dl) {
                    f32x4 v = ((const f32x4*)sl)[dl * 576 + j];
                    #pragma unroll
                    for (int e = 0; e < 4; ++e)
                        accD[s][dl & 1][e] = fminf(accD[s][dl & 1][e], v[e]);
                }
            }
        }
        if (t < 192) {
            const int d = part * 16 + q * 4 + dlh;
            {   // H: min over h at fixed (dlh, w=wh)
                const float* pb = sl + dlh * HD + wh;
                float m0 = 3e38f, m1 = 3e38f;
                #pragma unroll
                for (int h = 0; h < NDIM; h += 2) {
                    m0 = fminf(m0, pb[h * NDIM]);
                    m1 = fminf(m1, pb[(h + 1) * NDIM]);
                }
                tabH[(size_t)bc * 2 * HD + d * NDIM + wh]      = m0;
                tabH[(size_t)bc * 2 * HD + HD + d * NDIM + wh] = m1;
            }
            {   // W: min over w at fixed (dlh, h=wh)
                const f32x4* pr = (const f32x4*)(sl + dlh * HD + wh * NDIM);
                const int rot = wh % 12;
                float m0 = 3e38f, m1 = 3e38f;
                #pragma unroll
                for (int j = 0; j < 12; ++j) {
                    int jj = j + rot; if (jj >= 12) jj -= 12;
                    f32x4 v = pr[jj];
                    m0 = fminf(m0, fminf(v[0], v[2]));
                    m1 = fminf(m1, fminf(v[1], v[3]));
                }
                tabW[(size_t)bc * 2 * HD + d * NDIM + wh]      = m0;
                tabW[(size_t)bc * 2 * HD + HD + d * NDIM + wh] = m1;
            }
        }
        __syncthreads();
    }

    float* tDo = tabDp + ((size_t)part * 256 + bc) * 2 * HD;
    #pragma unroll
    for (int s = 0; s < 3; ++s) {
        const int j = t + s * 256;
        if (j < 576) {
            *((f32x4*)(tDo + j * 4))      = accD[s][0];
            *((f32x4*)(tDo + HD + j * 4)) = accD[s][1];
        }
    }
}

// ---------------- Kernel 2: element pass -> ybf [b][2C][SVOL] bf16 ----------------
__global__ __launch_bounds__(256) void elem_kernel(const float* __restrict__ x,
                                                   const float* __restrict__ tabDp,
                                                   const float* __restrict__ tabH,
                                                   const float* __restrict__ tabW,
                                                   ushort_t* __restrict__ ybf) {
    __shared__ __align__(16) float sD[2 * HD];
    __shared__ __align__(16) float sH[2 * 384];
    __shared__ __align__(16) float sW[2 * 384];
    const int slab = blockIdx.x;    // 0..5
    const int bc   = blockIdx.y;    // 0..255
    const int t    = threadIdx.x;
    const int b = bc >> 7, c = bc & 127;

    const float* tD0 = tabDp + ((size_t)0 * 256 + bc) * 2 * HD;
    const float* tD1 = tabDp + ((size_t)1 * 256 + bc) * 2 * HD;
    const float* tD2 = tabDp + ((size_t)2 * 256 + bc) * 2 * HD;
    for (int i = t; i < 2 * HD / 4; i += 256) {
        f32x4 a = ((const f32x4*)tD0)[i];
        f32x4 d1 = ((const f32x4*)tD1)[i];
        f32x4 d2 = ((const f32x4*)tD2)[i];
        f32x4 m;
        #pragma unroll
        for (int j = 0; j < 4; ++j) m[j] = fminf(a[j], fminf(d1[j], d2[j]));
        ((f32x4*)sD)[i] = m;
    }
    const float* tH = tabH + (size_t)bc * 2 * HD;
    const float* tW = tabW + (size_t)bc * 2 * HD;
    for (int i = t; i < 96; i += 256) {
        ((f32x4*)sH)[i]      = ((const f32x4*)(tH + slab * 384))[i];
        ((f32x4*)sH)[96 + i] = ((const f32x4*)(tH + HD + slab * 384))[i];
        ((f32x4*)sW)[i]      = ((const f32x4*)(tW + slab * 384))[i];
        ((f32x4*)sW)[96 + i] = ((const f32x4*)(tW + HD + slab * 384))[i];
    }
    __syncthreads();

    const float* __restrict__ xp = x + (size_t)bc * SVOL + (size_t)slab * 8 * HD;
    ushort_t* yx = ybf + (size_t)(b * 256 + c) * SVOL + (size_t)slab * 8 * HD;
    ushort_t* yj = yx + (size_t)128 * SVOL;

    for (int i4 = t; i4 < 8 * HD / 4; i4 += 256) {
        const int s = i4 * 4;
        const int dl = s / HD;
        const int r  = s - dl * HD;
        const int h  = r / NDIM;
        const int w0 = r - h * NDIM;
        const int pd = dl & 1, ph = h & 1;

        f32x4 v  = *(const f32x4*)(xp + s);
        f32x4 mD = *(const f32x4*)(sD + pd * HD + r);
        f32x4 mH = *(const f32x4*)(sH + ph * 384 + dl * NDIM + w0);
        const float mW0 = sW[dl * NDIM + h];
        const float mW1 = sW[384 + dl * NDIM + h];

        union { __hip_bfloat16 h4[4]; uint2 u; } ox, oj;
        #pragma unroll
        for (int j = 0; j < 4; ++j) {
            const float mm  = fminf(mD[j], fminf(mH[j], (j & 1) ? mW1 : mW0));
            const float xjv = fmaxf(0.0f, v[j] - mm);
            ox.h4[j] = __float2bfloat16(v[j]);
            oj.h4[j] = __float2bfloat16(xjv);
        }
        *(uint2*)(yx + s) = ox.u;
        *(uint2*)(yj + s) = oj.u;
    }
}

// ---------------- Kernel 3: GEMM, TPB tiles/block, double-buffered, swapped MFMA ----------------
// Tile 128o x 64s; LDS [buf][cq 0..63][sq 0..3][row 0..3][col 0..15] ushort = 2 x 32 KB.
#define TPB 4
__global__ __launch_bounds__(256, 2) void gemm_kernel(const ushort_t* __restrict__ ybf,
                                                      const ushort_t* __restrict__ Wb,
                                                      const float* __restrict__ bias,
                                                      float* __restrict__ out) {
    __shared__ __align__(1024) ushort_t ytile[2][16384];   // 64 KB
    const int tile0 = blockIdx.x * TPB;
    const int b  = blockIdx.y;
    const int t  = threadIdx.x;
    const int wid = t >> 6, lane = t & 63;   // 4 waves
    const ushort_t* __restrict__ yb = ybf + (size_t)b * 256 * SVOL;

    const int wm = wid;                      // 32-o strip per wave
    const int l15 = lane & 15, l4 = lane >> 4;

    // W-frags for this wave's 32-o strip: held in regs for all TPB tiles.
    const ushort_t* wp = Wb + (size_t)(wm * 32 + l15) * 256 + l4 * 8;
    bf16x8 aw[2][8];
    #pragma unroll
    for (int m = 0; m < 2; ++m)
        #pragma unroll
        for (int kk = 0; kk < 8; ++kk)
            aw[m][kk] = *(const bf16x8*)(wp + ((size_t)m * 16 * 256 + kk * 32));
    float bv[2];
    #pragma unroll
    for (int m = 0; m < 2; ++m) bv[m] = bias[wm * 32 + m * 16 + l15];

    // Staging lane map (per wave 8 instrs of 1 KB, linear LDS dest)
    const int g    = lane >> 5;
    const int l5   = lane & 31;
    const int sq   = l5 >> 3;
    const int row  = (l5 >> 1) & 3;
    const int colh = l5 & 1;

#define STAGE(buf, tile)                                                              \
    {                                                                                 \
        const int s0_ = (tile) * 64;                                                  \
        _Pragma("unroll")                                                             \
        for (int it = 0; it < 8; ++it) {                                              \
            const int cq0 = (it * 4 + wid) * 2;                                       \
            const int c   = (cq0 + g) * 4 + row;                                      \
            const ushort_t* src = yb + (size_t)c * SVOL + (s0_ + sq * 16 + colh * 8); \
            __builtin_amdgcn_global_load_lds(                                         \
                (const __attribute__((address_space(1))) void*)src,                   \
                (__attribute__((address_space(3))) void*)&ytile[buf][cq0 * 256],      \
                16, 0, 0);                                                            \
        }                                                                             \
    }

    const uint_t lds_base = (uint_t)(uintptr_t)(__attribute__((address_space(3))) ushort_t*)&ytile[0][0];
    const uint_t addr0 = lds_base + (uint_t)(l4 * 1024 + l15 * 8);
    float* ob = out + (size_t)b * 128 * SVOL;

    STAGE(0, tile0)

    #pragma unroll
    for (int tt = 0; tt < TPB; ++tt) {
        __builtin_amdgcn_s_barrier();            // all waves done reading buf[(tt)&1]'s previous tenant
        if (tt + 1 < TPB) STAGE((tt + 1) & 1, tile0 + tt + 1)
        __builtin_amdgcn_sched_barrier(0);
        // outstanding (oldest->newest): [stage(tt) 8][stores(tt-1) 8][stage(tt+1) 8]
        if (tt == 0 || tt + 1 == TPB) asm volatile("s_waitcnt vmcnt(8)" ::: "memory");
        else                          asm volatile("s_waitcnt vmcnt(16)" ::: "memory");
        __builtin_amdgcn_sched_barrier(0);
        __builtin_amdgcn_s_barrier();            // all waves' tile-tt data in LDS

        const uint_t addrB = addr0 + (uint_t)((tt & 1) * 32768);
        f32x4 acc[4][2] = {};
        #pragma unroll
        for (int ph = 0; ph < 2; ++ph) {
            u32x2 lo[4][4], hi[4][4];
            #pragma unroll
            for (int kk = 0; kk < 4; ++kk)
                #pragma unroll
                for (int n = 0; n < 4; ++n) {
                    const uint_t ad = addrB + (uint_t)((ph * 4 + kk) * 4096 + n * 128);
                    asm volatile("ds_read_b64_tr_b16 %0, %2 offset:0\n\t"
                                 "ds_read_b64_tr_b16 %1, %2 offset:512"
                                 : "=&v"(lo[kk][n]), "=&v"(hi[kk][n]) : "v"(ad) : "memory");
                }
            asm volatile("s_waitcnt lgkmcnt(0)" ::: "memory");
            __builtin_amdgcn_sched_barrier(0);
            #pragma unroll
            for (int kk = 0; kk < 4; ++kk)
                #pragma unroll
                for (int n = 0; n < 4; ++n) {
                    union { u32x2 u2[2]; bf16x8 v; } cvt;
                    cvt.u2[0] = lo[kk][n]; cvt.u2[1] = hi[kk][n];
                    #pragma unroll
                    for (int m = 0; m < 2; ++m)   // swapped operands: D rows = s
                        acc[n][m] = __builtin_amdgcn_mfma_f32_16x16x32_bf16(cvt.v, aw[m][ph * 4 + kk], acc[n][m], 0, 0, 0);
                }
        }

        const int s_b = (tile0 + tt) * 64;
        #pragma unroll
        for (int n = 0; n < 4; ++n)
            #pragma unroll
            for (int m = 0; m < 2; ++m) {
                const int o = wm * 32 + m * 16 + l15;
                const int s = s_b + n * 16 + l4 * 4;
                f32x4 r;
                #pragma unroll
                for (int j = 0; j < 4; ++j) r[j] = fmaxf(acc[n][m][j] + bv[m], 0.0f);
                *(f32x4*)(ob + (size_t)o * SVOL + s) = r;
            }
    }
#undef STAGE
}

extern "C" void kernel_launch(void* const* d_in, const int* in_sizes, int n_in,
                              void* d_out, int out_size, void* d_ws, size_t ws_size,
                              hipStream_t stream) {
    const float* x    = (const float*)d_in[0];
    const float* W    = (const float*)d_in[1];
    const float* bias = (const float*)d_in[2];
    float* out = (float*)d_out;

    ushort_t* ybf = (ushort_t*)d_ws;                                       // 113.25 MB
    ushort_t* Wb  = (ushort_t*)((char*)d_ws + (size_t)2 * 256 * SVOL * 2); // 64 KB

    float* tabDp = (float*)d_out;                       // 13.5 MB
    float* tabH  = tabDp + (size_t)3 * 256 * 2 * HD;    // 4.5 MB
    float* tabW  = tabH  + (size_t)256 * 2 * HD;        // 4.5 MB

    wconv_kernel<<<128, 256, 0, stream>>>(W, Wb);
    tables_kernel<<<dim3(256, 3), 256, 0, stream>>>(x, tabDp, tabH, tabW);
    elem_kernel<<<dim3(6, 256), 256, 0, stream>>>(x, tabDp, tabH, tabW, ybf);
    gemm_kernel<<<dim3(SVOL / 64 / TPB, 2), 256, 0, stream>>>(ybf, Wb, bias, out);
}